// Round 1
// baseline (350.477 us; speedup 1.0000x reference)
//
#include <hip/hip_runtime.h>

// ---------------------------------------------------------------------------
// SlotAttention on MI355X (gfx950).
// GEMMs in bf16 MFMA (16x16x32), everything else fp32 vector.
// Fragment layouts per learn_hip m89/m97 (ref-verified):
//   A/B operand: idx = lane&15 (m or n), k = (lane>>4)*8 + j  (8 contiguous bf16)
//   C/D:         col = lane&15, row = (lane>>4)*4 + reg
// ---------------------------------------------------------------------------

typedef __attribute__((ext_vector_type(8))) __bf16 bf16x8;
typedef __attribute__((ext_vector_type(4))) float  f32x4;

static __device__ __forceinline__ unsigned short f2bf(float f) {
    unsigned int x = __float_as_uint(f);
    x = (x + 0x7fffu + ((x >> 16) & 1u)) >> 16;   // RN-even
    return (unsigned short)x;
}

// ---------------- prep: weights -> bf16, slots = mu + exp(ls)*noise ----------
__global__ __launch_bounds__(256) void prep_kernel(
    const float* __restrict__ Wk, const float* __restrict__ Wv,
    const float* __restrict__ Wq, const float* __restrict__ wih,
    const float* __restrict__ whh, const float* __restrict__ w1,
    const float* __restrict__ w2, const float* __restrict__ noise,
    const float* __restrict__ mu, const float* __restrict__ ls,
    unsigned short* __restrict__ kvW_bf, unsigned short* __restrict__ Wq_bf,
    unsigned short* __restrict__ wih_bf, unsigned short* __restrict__ whh_bf,
    unsigned short* __restrict__ w1_bf, unsigned short* __restrict__ w2_bf,
    float* __restrict__ slots)
{
    int gid = blockIdx.x * 256 + threadIdx.x;
    if      (gid <   65536) kvW_bf[gid]          = f2bf(Wk[gid]);
    else if (gid <  131072) kvW_bf[gid]          = f2bf(Wv[gid -   65536]);
    else if (gid <  196608) Wq_bf[gid - 131072]  = f2bf(Wq[gid -  131072]);
    else if (gid <  393216) wih_bf[gid - 196608] = f2bf(wih[gid - 196608]);
    else if (gid <  589824) whh_bf[gid - 393216] = f2bf(whh[gid - 393216]);
    else if (gid <  851968) w1_bf[gid - 589824]  = f2bf(w1[gid -  589824]);
    else if (gid < 1114112) w2_bf[gid - 851968]  = f2bf(w2[gid -  851968]);
    else if (gid < 1179648) {
        int i = gid - 1114112;
        int d = i & 255;
        slots[i] = mu[d] + expf(ls[d]) * noise[i];
    }
}

// ---------------- LayerNorm over 256-elem rows -> bf16 ----------------------
__global__ __launch_bounds__(256) void ln_bf16_kernel(
    const float* __restrict__ x, unsigned short* __restrict__ y,
    const float* __restrict__ g, const float* __restrict__ b)
{
    __shared__ float red[8];
    int row = blockIdx.x, t = threadIdx.x;
    float v = x[(size_t)row * 256 + t];
    float s = v, ss = v * v;
    #pragma unroll
    for (int o = 32; o > 0; o >>= 1) { s += __shfl_down(s, o); ss += __shfl_down(ss, o); }
    if ((t & 63) == 0) { red[t >> 6] = s; red[4 + (t >> 6)] = ss; }
    __syncthreads();
    float S = red[0] + red[1] + red[2] + red[3];
    float SS = red[4] + red[5] + red[6] + red[7];
    float mean = S * (1.f / 256.f);
    float var  = SS * (1.f / 256.f) - mean * mean;
    float rstd = rsqrtf(var + 1e-5f);
    y[(size_t)row * 256 + t] = f2bf((v - mean) * rstd * g[t] + b[t]);
}

// ---------------- bf16 MFMA GEMM: C[M,N] = A[M,K] @ B[N,K]^T ----------------
// EPI: 0 = fp32 store; 1 = +bias fp32; 2 = +bias, relu -> bf16; 3 = +bias+res fp32
template<int EPI>
__global__ __launch_bounds__(256) void gemm128(
    const unsigned short* __restrict__ A, const unsigned short* __restrict__ B,
    float* __restrict__ C, unsigned short* __restrict__ Cbf,
    const float* __restrict__ bias, const float* __restrict__ res,
    int M, int N, int K)
{
    __shared__ unsigned short As[128 * 32], Bs[128 * 32];
    const int m0 = blockIdx.x * 128, n0 = blockIdx.y * 128;
    const int t = threadIdx.x, wave = t >> 6, lane = t & 63;
    const int qr = (wave >> 1) * 64, qc = (wave & 1) * 64;
    const int lr = lane & 15, lq = lane >> 4;
    f32x4 acc[4][4] = {};
    const int sr = t >> 2, sc = (t & 3) * 8;
    for (int k0 = 0; k0 < K; k0 += 32) {
        __syncthreads();
        uint4 a0 = *(const uint4*)(A + (size_t)(m0 + sr) * K + k0 + sc);
        uint4 a1 = *(const uint4*)(A + (size_t)(m0 + sr + 64) * K + k0 + sc);
        uint4 b0 = *(const uint4*)(B + (size_t)(n0 + sr) * K + k0 + sc);
        uint4 b1 = *(const uint4*)(B + (size_t)(n0 + sr + 64) * K + k0 + sc);
        *(uint4*)(As + sr * 32 + sc) = a0;
        *(uint4*)(As + (sr + 64) * 32 + sc) = a1;
        *(uint4*)(Bs + sr * 32 + sc) = b0;
        *(uint4*)(Bs + (sr + 64) * 32 + sc) = b1;
        __syncthreads();
        bf16x8 af[4], bv[4];
        #pragma unroll
        for (int i = 0; i < 4; i++) af[i] = *(const bf16x8*)(As + (qr + i * 16 + lr) * 32 + lq * 8);
        #pragma unroll
        for (int i = 0; i < 4; i++) bv[i] = *(const bf16x8*)(Bs + (qc + i * 16 + lr) * 32 + lq * 8);
        #pragma unroll
        for (int i = 0; i < 4; i++)
            #pragma unroll
            for (int j = 0; j < 4; j++)
                acc[i][j] = __builtin_amdgcn_mfma_f32_16x16x32_bf16(af[i], bv[j], acc[i][j], 0, 0, 0);
    }
    #pragma unroll
    for (int i = 0; i < 4; i++)
        #pragma unroll
        for (int j = 0; j < 4; j++) {
            int col = n0 + qc + j * 16 + lr;
            #pragma unroll
            for (int r = 0; r < 4; r++) {
                int row = m0 + qr + i * 16 + lq * 4 + r;
                size_t idx = (size_t)row * N + col;
                float v = acc[i][j][r];
                if      (EPI == 0) C[idx] = v;
                else if (EPI == 1) C[idx] = v + bias[col];
                else if (EPI == 2) Cbf[idx] = f2bf(fmaxf(v + bias[col], 0.f));
                else               C[idx] = v + bias[col] + res[idx];
            }
        }
}

// 64x64-tile variant for the small (M=256) GEMMs: more blocks in flight.
template<int EPI>
__global__ __launch_bounds__(256) void gemm64(
    const unsigned short* __restrict__ A, const unsigned short* __restrict__ B,
    float* __restrict__ C, unsigned short* __restrict__ Cbf,
    const float* __restrict__ bias, const float* __restrict__ res,
    int M, int N, int K)
{
    __shared__ unsigned short As[64 * 32], Bs[64 * 32];
    const int m0 = blockIdx.x * 64, n0 = blockIdx.y * 64;
    const int t = threadIdx.x, wave = t >> 6, lane = t & 63;
    const int lr = lane & 15, lq = lane >> 4;
    f32x4 acc[4] = {};
    const int sr = t >> 2, sc = (t & 3) * 8;
    for (int k0 = 0; k0 < K; k0 += 32) {
        __syncthreads();
        uint4 a0 = *(const uint4*)(A + (size_t)(m0 + sr) * K + k0 + sc);
        uint4 b0 = *(const uint4*)(B + (size_t)(n0 + sr) * K + k0 + sc);
        *(uint4*)(As + sr * 32 + sc) = a0;
        *(uint4*)(Bs + sr * 32 + sc) = b0;
        __syncthreads();
        bf16x8 af = *(const bf16x8*)(As + (wave * 16 + lr) * 32 + lq * 8);
        #pragma unroll
        for (int j = 0; j < 4; j++) {
            bf16x8 bv = *(const bf16x8*)(Bs + (j * 16 + lr) * 32 + lq * 8);
            acc[j] = __builtin_amdgcn_mfma_f32_16x16x32_bf16(af, bv, acc[j], 0, 0, 0);
        }
    }
    #pragma unroll
    for (int j = 0; j < 4; j++) {
        int col = n0 + j * 16 + lr;
        #pragma unroll
        for (int r = 0; r < 4; r++) {
            int row = m0 + wave * 16 + lq * 4 + r;
            size_t idx = (size_t)row * N + col;
            float v = acc[j][r];
            if      (EPI == 0) C[idx] = v;
            else if (EPI == 1) C[idx] = v + bias[col];
            else if (EPI == 2) Cbf[idx] = f2bf(fmaxf(v + bias[col], 0.f));
            else               C[idx] = v + bias[col] + res[idx];
        }
    }
}

// --------- dots + softmax(over slots) + EPS + partial weighted-sum of v -----
// grid (8 chunks, 32 batches); chunk = 128 tokens.
__global__ __launch_bounds__(256) void attn_kernel(
    const float* __restrict__ q, const float* __restrict__ kv,
    float* __restrict__ upart, float* __restrict__ rspart)
{
    __shared__ float q_s[8][260];   // +4 pad: conflict-free
    __shared__ float d_s[8][132];
    int chunk = blockIdx.x, b = blockIdx.y, t = threadIdx.x;
    {   // load q rows for this batch (8 x 256 fp32)
        int i = t >> 5, c0 = (t & 31) * 8;
        const float* qr = q + (size_t)(b * 8 + i) * 256 + c0;
        *(float4*)&q_s[i][c0]     = *(const float4*)(qr);
        *(float4*)&q_s[i][c0 + 4] = *(const float4*)(qr + 4);
    }
    __syncthreads();
    int i = t & 7, jj = t >> 3;      // i: slot, jj: 0..31
    int j0 = chunk * 128;
    const float4* qrow = (const float4*)&q_s[i][0];
    for (int g = 0; g < 4; g++) {
        int jl = g * 32 + jj;
        const float4* krow = (const float4*)(kv + ((size_t)b * 1024 + j0 + jl) * 512);
        float a0 = 0, a1 = 0, a2 = 0, a3 = 0;
        #pragma unroll 8
        for (int dd = 0; dd < 64; dd++) {
            float4 qv = qrow[dd];
            float4 kk = krow[dd];
            a0 += qv.x * kk.x; a1 += qv.y * kk.y; a2 += qv.z * kk.z; a3 += qv.w * kk.w;
        }
        d_s[i][jl] = (a0 + a1 + a2 + a3) * 0.0625f;   // SCALE = 256^-0.5
    }
    __syncthreads();
    if (t < 128) {    // softmax over the 8 slots for token t, + EPS
        float v[8], m = -1e30f;
        #pragma unroll
        for (int ii = 0; ii < 8; ii++) { v[ii] = d_s[ii][t]; m = fmaxf(m, v[ii]); }
        float s = 0.f;
        #pragma unroll
        for (int ii = 0; ii < 8; ii++) { v[ii] = __expf(v[ii] - m); s += v[ii]; }
        float inv = 1.f / s;
        #pragma unroll
        for (int ii = 0; ii < 8; ii++) d_s[ii][t] = v[ii] * inv + 1e-8f;
    }
    __syncthreads();
    if (t < 8) {      // per-slot partial row sum over this chunk
        float s = 0.f;
        for (int jl = 0; jl < 128; jl++) s += d_s[t][jl];
        rspart[((size_t)b * 8 + chunk) * 8 + t] = s;
    }
    {   // partial updates: acc[i] += w[i][j] * v[j][d], d = t
        float acc[8] = {0, 0, 0, 0, 0, 0, 0, 0};
        const float* vbase = kv + ((size_t)b * 1024 + j0) * 512 + 256 + t;
        for (int jl = 0; jl < 128; jl++) {
            float vv = vbase[(size_t)jl * 512];
            #pragma unroll
            for (int ii = 0; ii < 8; ii++) acc[ii] += d_s[ii][jl] * vv;
        }
        float* up = upart + (((size_t)b * 8 + chunk) * 8) * 256 + t;
        #pragma unroll
        for (int ii = 0; ii < 8; ii++) up[ii * 256] = acc[ii];
    }
}

// --------- combine partials, normalize; emit u_bf & h_bf (=slots_prev) ------
__global__ __launch_bounds__(256) void u2b_kernel(
    const float* __restrict__ upart, const float* __restrict__ rspart,
    const float* __restrict__ slots, unsigned short* __restrict__ u_bf,
    unsigned short* __restrict__ h_bf)
{
    int row = blockIdx.x, t = threadIdx.x;
    int b = row >> 3, i = row & 7;
    float acc = 0.f, rs = 0.f;
    #pragma unroll
    for (int c = 0; c < 8; c++) {
        acc += upart[((size_t)(b * 8 + c) * 8 + i) * 256 + t];
        rs  += rspart[(size_t)(b * 8 + c) * 8 + i];
    }
    u_bf[(size_t)row * 256 + t] = f2bf(acc / rs);
    h_bf[(size_t)row * 256 + t] = f2bf(slots[(size_t)row * 256 + t]);
}

// --------- fused GRU gates + in-place slots update + LN_ff -> bf16 ----------
__global__ __launch_bounds__(256) void gru_ln_kernel(
    const float* __restrict__ gi, const float* __restrict__ gh,
    float* __restrict__ slots, unsigned short* __restrict__ ff_bf,
    const float* __restrict__ g, const float* __restrict__ b)
{
    __shared__ float red[8];
    int row = blockIdx.x, t = threadIdx.x;
    const float* gir = gi + (size_t)row * 768;
    const float* ghr = gh + (size_t)row * 768;
    float ir = gir[t], iz = gir[256 + t], in_ = gir[512 + t];
    float hr = ghr[t], hz = ghr[256 + t], hn  = ghr[512 + t];
    float r = 1.f / (1.f + __expf(-(ir + hr)));
    float z = 1.f / (1.f + __expf(-(iz + hz)));
    float n = tanhf(in_ + r * hn);
    float h = slots[(size_t)row * 256 + t];
    float s = (1.f - z) * n + z * h;
    slots[(size_t)row * 256 + t] = s;
    float sm = s, ssq = s * s;
    #pragma unroll
    for (int o = 32; o > 0; o >>= 1) { sm += __shfl_down(sm, o); ssq += __shfl_down(ssq, o); }
    if ((t & 63) == 0) { red[t >> 6] = sm; red[4 + (t >> 6)] = ssq; }
    __syncthreads();
    float S = red[0] + red[1] + red[2] + red[3];
    float SS = red[4] + red[5] + red[6] + red[7];
    float mean = S * (1.f / 256.f);
    float var  = SS * (1.f / 256.f) - mean * mean;
    float rstd = rsqrtf(var + 1e-5f);
    ff_bf[(size_t)row * 256 + t] = f2bf((s - mean) * rstd * g[t] + b[t]);
}

// ---------------------------------------------------------------------------
extern "C" void kernel_launch(void* const* d_in, const int* in_sizes, int n_in,
                              void* d_out, int out_size, void* d_ws, size_t ws_size,
                              hipStream_t stream)
{
    const float* inputs  = (const float*)d_in[0];
    const float* noise   = (const float*)d_in[1];
    const float* mu      = (const float*)d_in[2];
    const float* ls      = (const float*)d_in[3];
    const float* Wq      = (const float*)d_in[4];
    const float* Wk      = (const float*)d_in[5];
    const float* Wv      = (const float*)d_in[6];
    const float* wih     = (const float*)d_in[7];
    const float* whh     = (const float*)d_in[8];
    const float* bih     = (const float*)d_in[9];
    const float* bhh     = (const float*)d_in[10];
    const float* w1      = (const float*)d_in[11];
    const float* b1      = (const float*)d_in[12];
    const float* w2      = (const float*)d_in[13];
    const float* b2      = (const float*)d_in[14];
    const float* ln_in_g = (const float*)d_in[15];
    const float* ln_in_b = (const float*)d_in[16];
    const float* ln_s_g  = (const float*)d_in[17];
    const float* ln_s_b  = (const float*)d_in[18];
    const float* ln_ff_g = (const float*)d_in[19];
    const float* ln_ff_b = (const float*)d_in[20];

    char* p = (char*)d_ws;
    auto alloc = [&](size_t bytes) -> char* {
        char* r = p; p += (bytes + 255) & ~(size_t)255; return r;
    };
    unsigned short* x_bf   = (unsigned short*)alloc((size_t)32768 * 256 * 2);
    float*          kv     = (float*)         alloc((size_t)32768 * 512 * 4);
    unsigned short* kvW_bf = (unsigned short*)alloc(512 * 256 * 2);
    unsigned short* Wq_bf  = (unsigned short*)alloc(256 * 256 * 2);
    unsigned short* wih_bf = (unsigned short*)alloc(768 * 256 * 2);
    unsigned short* whh_bf = (unsigned short*)alloc(768 * 256 * 2);
    unsigned short* w1_bf  = (unsigned short*)alloc(1024 * 256 * 2);
    unsigned short* w2_bf  = (unsigned short*)alloc(256 * 1024 * 2);
    float*          slots  = (float*)         alloc(256 * 256 * 4);
    unsigned short* s_bf   = (unsigned short*)alloc(256 * 256 * 2);
    float*          qbuf   = (float*)         alloc(256 * 256 * 4);
    float*          upart  = (float*)         alloc((size_t)32 * 8 * 8 * 256 * 4);
    float*          rspart = (float*)         alloc(32 * 8 * 8 * 4);
    unsigned short* u_bf   = (unsigned short*)alloc(256 * 256 * 2);
    unsigned short* h_bf   = (unsigned short*)alloc(256 * 256 * 2);
    float*          gi     = (float*)         alloc(256 * 768 * 4);
    float*          gh     = (float*)         alloc(256 * 768 * 4);
    unsigned short* ff_bf  = (unsigned short*)alloc(256 * 256 * 2);
    unsigned short* h1_bf  = (unsigned short*)alloc(256 * 1024 * 2);

    // one-time: weight conversion + slots init
    prep_kernel<<<4608, 256, 0, stream>>>(Wk, Wv, Wq, wih, whh, w1, w2, noise, mu, ls,
                                          kvW_bf, Wq_bf, wih_bf, whh_bf, w1_bf, w2_bf, slots);
    // LN(inputs) -> bf16
    ln_bf16_kernel<<<32768, 256, 0, stream>>>(inputs, x_bf, ln_in_g, ln_in_b);
    // kv = x_ln @ [Wk;Wv]^T   (fp32 out, [32768, 512], k = cols 0..255)
    gemm128<0><<<dim3(256, 4), 256, 0, stream>>>(x_bf, kvW_bf, kv, nullptr, nullptr, nullptr,
                                                 32768, 512, 256);

    for (int it = 0; it < 3; ++it) {
        ln_bf16_kernel<<<256, 256, 0, stream>>>(slots, s_bf, ln_s_g, ln_s_b);
        gemm64<0><<<dim3(4, 4), 256, 0, stream>>>(s_bf, Wq_bf, qbuf, nullptr, nullptr, nullptr,
                                                  256, 256, 256);
        attn_kernel<<<dim3(8, 32), 256, 0, stream>>>(qbuf, kv, upart, rspart);
        u2b_kernel<<<256, 256, 0, stream>>>(upart, rspart, slots, u_bf, h_bf);
        gemm64<1><<<dim3(4, 12), 256, 0, stream>>>(u_bf, wih_bf, gi, nullptr, bih, nullptr,
                                                   256, 768, 256);
        gemm64<1><<<dim3(4, 12), 256, 0, stream>>>(h_bf, whh_bf, gh, nullptr, bhh, nullptr,
                                                   256, 768, 256);
        gru_ln_kernel<<<256, 256, 0, stream>>>(gi, gh, slots, ff_bf, ln_ff_g, ln_ff_b);
        gemm64<2><<<dim3(4, 16), 256, 0, stream>>>(ff_bf, w1_bf, nullptr, h1_bf, b1, nullptr,
                                                   256, 1024, 256);
        float* dst = (it == 2) ? (float*)d_out : slots;
        gemm64<3><<<dim3(4, 4), 256, 0, stream>>>(h1_bf, w2_bf, dst, nullptr, b2, slots,
                                                  256, 256, 1024);
    }
}